// Round 2
// baseline (839.958 us; speedup 1.0000x reference)
//
#include <hip/hip_runtime.h>
#include <cstdint>
#include <cstddef>

// DimensionPruning: per-dim BH-FDR rejection count.
// importance[d] = #{m: C_d(m) >= m} + min{m: C_d(m) >= m} - 1  (0 if none)
// C_d(m) = #{i: u_i <= m}, u_i = ceil(p_i * n/alpha), p_i = Phi(-mu/sigma).
//
// Band-compaction design:
//   classify: stream mu,var. x = mu/var.
//     m <  2.4*v          -> u = 0   (s >= 16395 > 15360, 6.7% margin)
//     m >  6.0*v          -> u = 1   (s <= 0.002 -> ceil-clamp to 1), counted in
//                            32-way sharded per-dim u1 counters (no erfcf!)
//     else (band, ~12%)   -> append 4B entry to wave-sharded compact buffer.
//        x in [2.4, 8) spans exactly two float exponents (128, 129) ->
//        entry = mantissa(23b) << 9 | dim(9b); exponent implied by buffer.
//   erf: dense full-lane erfcf over ~6M compacted entries (bit-exact x
//        reconstruction), u16-packed histogram atomics (max bin ~6.5k << 65k).
//   scan: per-dim cumulative scan of packed hist (+u1 shard sum into bin 1).
// Overflowed appends (ws too small) are computed inline -> correct for any ws.

#define N_OBJ  100000
#define N_DIM  512
#define UCAP   15360
#define H32PD  (UCAP / 2)               // 7680 packed u32 per dim
#define H32TOT (N_DIM * H32PD)          // 3,932,160
#define U1S    32
#define U1TOT  (U1S * N_DIM)            // 16,384
#define NSH    64                       // compact shards
#define METAU32 (H32TOT + U1TOT + 2 * NSH)   // 3,948,672 u32 zeroed per launch

// bin-commit from exact x (identical fp sequence to the verified kernel)
__device__ __forceinline__ void bin_commit(float x, int d, unsigned int* hist32)
{
    const float p = 0.5f * erfcf(x * 0.70710678118654752f);
    const float s = p * 2000000.0f;     // p * n / alpha
    if (s <= (float)UCAP) {
        const int ui = (int)ceilf(s);
        const unsigned int u = (unsigned int)(ui < 1 ? 1 : ui);
        const unsigned int b = u - 1u;
        atomicAdd(&hist32[(size_t)d * H32PD + (b >> 1)], 1u << ((b & 1u) << 4));
    }
}

// ---------------- pass 0: zero hist + u1 + cursors ----------------
__global__ __launch_bounds__(256) void zero_kernel(uint4* __restrict__ p, int n4)
{
    const int i = blockIdx.x * 256 + threadIdx.x;
    if (i < n4) p[i] = make_uint4(0u, 0u, 0u, 0u);
}

// ---------------- pass 1: classify + compact (no erfcf on the hot path) ----
__global__ __launch_bounds__(256) void classify_kernel(
    const float4* __restrict__ mu4, const float4* __restrict__ var4,
    unsigned int* __restrict__ hist32, unsigned int* __restrict__ u1,
    unsigned int* __restrict__ cur,
    unsigned int* __restrict__ bufA, unsigned int* __restrict__ bufB,
    int capA, int capB)
{
    __shared__ unsigned int eA[1024], eB[1024];
    __shared__ unsigned int cA, cB, bA, bB;
    const int tid = threadIdx.x;
    if (tid == 0) { cA = 0u; cB = 0u; }
    __syncthreads();

    const size_t f4 = (size_t)blockIdx.x * 256 + tid;   // 12.8M float4 exactly
    const float4 m4 = mu4[f4];
    const float4 v4 = var4[f4];
    const int d0 = ((int)(f4 & 127)) << 2;
    const float ms[4] = {m4.x, m4.y, m4.z, m4.w};
    const float vs[4] = {v4.x, v4.y, v4.z, v4.w};
    const int ush = (blockIdx.x & (U1S - 1)) * N_DIM;

    #pragma unroll
    for (int j = 0; j < 4; ++j) {
        const float m = ms[j], v = vs[j];
        if (m < 2.4f * v) continue;                    // u = 0
        if (m > 6.0f * v) {                            // u = 1
            atomicAdd(&u1[ush + d0 + j], 1u);
        } else {                                       // band: compact
            const float x = m / v;
            const unsigned int xb = __float_as_uint(x);
            const unsigned int ent = ((xb & 0x7FFFFFu) << 9) | (unsigned int)(d0 + j);
            if (((xb >> 23) & 0xFFu) == 128u) eA[atomicAdd(&cA, 1u)] = ent;
            else                              eB[atomicAdd(&cB, 1u)] = ent;
        }
    }
    __syncthreads();
    const int sh = blockIdx.x & (NSH - 1);
    if (tid == 0 && cA) bA = atomicAdd(&cur[sh], cA);
    if (tid == 1 && cB) bB = atomicAdd(&cur[NSH + sh], cB);
    __syncthreads();

    for (unsigned int i = tid; i < cA; i += 256) {
        const unsigned int pos = bA + i;
        if (pos < (unsigned int)capA) bufA[(size_t)sh * capA + pos] = eA[i];
        else {  // overflow: compute inline (rare / ws-too-small fallback)
            const unsigned int w = eA[i];
            bin_commit(__uint_as_float((128u << 23) | (w >> 9)), (int)(w & 511u), hist32);
        }
    }
    for (unsigned int i = tid; i < cB; i += 256) {
        const unsigned int pos = bB + i;
        if (pos < (unsigned int)capB) bufB[(size_t)sh * capB + pos] = eB[i];
        else {
            const unsigned int w = eB[i];
            bin_commit(__uint_as_float((129u << 23) | (w >> 9)), (int)(w & 511u), hist32);
        }
    }
}

// ---------------- pass 2: dense erfcf over compacted entries ----------------
__global__ __launch_bounds__(256) void erf_kernel(
    const unsigned int* __restrict__ bufA, const unsigned int* __restrict__ bufB,
    const unsigned int* __restrict__ cur, unsigned int* __restrict__ hist32,
    int capA, int capB)
{
    const int bid = blockIdx.x;                 // grid = 2048 = 64 sh * 2 buf * 16
    const int sh  = bid & (NSH - 1);
    const int h   = (bid >> 6) & 1;
    const int sub = bid >> 7;                   // 0..15
    const unsigned int cap = (unsigned int)(h ? capB : capA);
    unsigned int len = cur[h * NSH + sh];
    if (len > cap) len = cap;
    const unsigned int* __restrict__ buf =
        h ? bufB + (size_t)sh * capB : bufA + (size_t)sh * capA;
    const unsigned int expw = (h ? 129u : 128u) << 23;
    for (unsigned int i = (unsigned int)(sub * 256 + threadIdx.x); i < len; i += 4096)
    {
        const unsigned int w = buf[i];
        bin_commit(__uint_as_float(expw | (w >> 9)), (int)(w & 511u), hist32);
    }
}

// ---------------- pass 3: per-dim cumulative scan ----------------
__global__ __launch_bounds__(256) void scan_kernel(
    const unsigned int* __restrict__ hist32, const unsigned int* __restrict__ u1,
    int* __restrict__ out)
{
    __shared__ unsigned int wsum[4], redc[4], redm[4], u1sh;
    const int tid = threadIdx.x, lane = tid & 63, wid = tid >> 6;
    const int d = blockIdx.x;
    const unsigned int* __restrict__ h = hist32 + (size_t)d * H32PD;

    // sum the 32 u1 shards for this dim (wave 0)
    unsigned int uv = (tid < U1S) ? u1[tid * N_DIM + d] : 0u;
    #pragma unroll
    for (int o = 16; o > 0; o >>= 1) uv += __shfl_down(uv, o, 64);
    if (tid == 0) u1sh = uv;
    __syncthreads();
    const unsigned int u1add = u1sh;

    unsigned int running = 0, tcount = 0, tmin = 0xFFFFFFFFu;
    for (int u0 = 0; u0 < UCAP; u0 += 2048) {          // 8 chunks of 2048 bins
        const int w0 = (u0 >> 1) + (tid << 2);
        uint4 wv = make_uint4(0u, 0u, 0u, 0u);
        if (w0 < H32PD) wv = *(const uint4*)&h[w0];    // tail chunk: tid<128 only
        unsigned int cc[8] = {wv.x & 0xFFFFu, wv.x >> 16, wv.y & 0xFFFFu, wv.y >> 16,
                              wv.z & 0xFFFFu, wv.z >> 16, wv.w & 0xFFFFu, wv.w >> 16};
        if (u0 == 0 && tid == 0) cc[0] += u1add;       // bin m=1 gets u1 total
        unsigned int ls = 0;
        #pragma unroll
        for (int j = 0; j < 8; ++j) ls += cc[j];

        unsigned int sc = ls;                          // wave64 inclusive scan
        #pragma unroll
        for (int dd = 1; dd < 64; dd <<= 1) {
            const unsigned int vv = __shfl_up(sc, dd, 64);
            if (lane >= dd) sc += vv;
        }
        if (lane == 63) wsum[wid] = sc;
        __syncthreads();

        unsigned int woff = 0, btot = 0;
        #pragma unroll
        for (int w = 0; w < 4; ++w) {
            const unsigned int s = wsum[w];
            btot += s;
            if (w < wid) woff += s;
        }

        unsigned int P = running + woff + (sc - ls);   // exclusive prefix
        #pragma unroll
        for (int j = 0; j < 8; ++j) {
            P += cc[j];                                // inclusive C(m)
            const unsigned int mm = (unsigned int)(u0 + (tid << 3) + j + 1);
            if (mm <= (unsigned int)UCAP && P >= mm) {
                tcount++; if (mm < tmin) tmin = mm;
            }
        }
        running += btot;
        __syncthreads();
    }

    #pragma unroll
    for (int dd = 32; dd > 0; dd >>= 1) {
        tcount += __shfl_down(tcount, dd, 64);
        const unsigned int om = __shfl_down(tmin, dd, 64);
        if (om < tmin) tmin = om;
    }
    if (lane == 0) { redc[wid] = tcount; redm[wid] = tmin; }
    __syncthreads();
    if (tid == 0) {
        const unsigned int tot = redc[0] + redc[1] + redc[2] + redc[3];
        const unsigned int mn  = min(min(redm[0], redm[1]), min(redm[2], redm[3]));
        out[d] = tot ? (int)(tot + mn - 1u) : 0;
    }
}

extern "C" void kernel_launch(void* const* d_in, const int* in_sizes, int n_in,
                              void* d_out, int out_size, void* d_ws, size_t ws_size,
                              hipStream_t stream)
{
    const float4* mu4  = (const float4*)d_in[0];
    const float4* var4 = (const float4*)d_in[1];
    int* out = (int*)d_out;

    unsigned int* W      = (unsigned int*)d_ws;
    unsigned int* hist32 = W;
    unsigned int* u1     = W + H32TOT;
    unsigned int* cur    = W + H32TOT + U1TOT;
    unsigned int* bufA   = W + METAU32;

    const size_t ws_u32 = ws_size / 4;
    const size_t remain = (ws_u32 > (size_t)METAU32) ? ws_u32 - METAU32 : 0;
    long capAl = (long)(remain * 7 / 10 / NSH);       // expected ~70k, cap ~98k
    long capBl = (long)(remain * 3 / 10 / NSH);       // expected ~26k, cap ~42k
    if (capAl < 1) capAl = 1;
    if (capBl < 1) capBl = 1;
    const int capA = (int)capAl, capB = (int)capBl;
    unsigned int* bufB = bufA + (size_t)capA * NSH;

    const int n4 = METAU32 / 4;                        // 987,168
    zero_kernel<<<(n4 + 255) / 256, 256, 0, stream>>>((uint4*)W, n4);
    classify_kernel<<<N_OBJ * N_DIM / 1024, 256, 0, stream>>>(
        mu4, var4, hist32, u1, cur, bufA, bufB, capA, capB);
    erf_kernel<<<2048, 256, 0, stream>>>(bufA, bufB, cur, hist32, capA, capB);
    scan_kernel<<<N_DIM, 256, 0, stream>>>(hist32, u1, out);
}

// Round 3
// 706.231 us; speedup vs baseline: 1.1894x; 1.1894x over previous
//
#include <hip/hip_runtime.h>
#include <cstdint>
#include <cstddef>

// DimensionPruning: per-dim BH-FDR rejection count.
// importance[d] = #{m: C_d(m) >= m} + min{m: C_d(m) >= m} - 1  (0 if none)
// C_d(m) = #{i: u_i <= m}, u_i = ceil(p_i * n/alpha), p_i = Phi(-mu/sigma).
//
// Round-3 design (post-mortem driven):
//  * classify: lean grid-stride stream. NO LDS, NO syncthreads, no flush
//    phase (round-2's block machinery was the stall: 305us at 11% BW /
//    17.6% VALU). Band elements (x=mu/var in [2.4,6], ~11%) append a 4B
//    entry (24 x-bits; exp in {128,129} since [2.4,6] subset [2,8)) into a
//    per-(dim, blockIdx&7) bucket via cursor atomic-return; u=1 elements
//    (x>6, ~5%) bump a sharded per-dim counter. Lanes cover distinct dims
//    -> distinct cursors -> atomics run in parallel.
//  * fdr: one block per dim. LDS u16-packed histogram (30KB) built from
//    the dim's own compacted entries with dense erfcf (u==1 in registers),
//    then the scan runs entirely in LDS. The 15.7MB global atomic hist
//    (and its zero pass + dirty-line re-read, ~530us in round 2) is gone.
//  * exactness: same gates / same fp sequences as the verified round-2
//    kernel. Gate margins: s(2.4)=16395>15360 (u=0 both paths);
//    s(6)=0.002 -> ceil-clamp 1 (u=1 both paths). Bucket cap ~3250 vs
//    mean 1363 (+30 sigma); overflow entries go to a global list that
//    every fdr block scans (expected empty) -> exact for any sane ws.

#define N_OBJ  100000
#define N_DIM  512
#define UCAP   15360
#define H32PD  (UCAP / 2)            // 7680 packed-u16 words per dim (LDS)
#define NSH    8                     // shards (~XCD via blockIdx&7)
#define NBUCK  (N_DIM * NSH)         // 4096 buckets / cursors / u1 counters
#define OVFCAP 32768

// ws u32 layout: [0,4096) cur | [4096,8192) u1c | [8192] ovf_cnt |
//                [8200, 8200+2*OVFCAP) ovf pairs | [HDRU32, ...) buckets
#define HDRU32 (8200 + 2 * OVFCAP)

// ---------------- pass 0: zero cursors + u1 counters + ovf count ---------
__global__ __launch_bounds__(256) void zero_kernel(unsigned int* __restrict__ w)
{
    const int i = blockIdx.x * 256 + threadIdx.x;
    if (i < 8193) w[i] = 0u;
}

// ---------------- pass 1: lean classify + compact ----------------
__global__ __launch_bounds__(256) void classify_kernel(
    const float4* __restrict__ mu4, const float4* __restrict__ var4,
    unsigned int* __restrict__ W, int cap)
{
    unsigned int* __restrict__ cur     = W;
    unsigned int* __restrict__ u1c     = W + 4096;
    unsigned int* __restrict__ ovf_cnt = W + 8192;
    unsigned int* __restrict__ ovf     = W + 8200;
    unsigned int* __restrict__ buf     = W + HDRU32;

    const int sh = blockIdx.x & (NSH - 1);
    const size_t nslot  = (size_t)N_OBJ * N_DIM / 4;   // 12,800,000
    const size_t stride = (size_t)gridDim.x * 256;

    for (size_t s = (size_t)blockIdx.x * 256 + threadIdx.x; s < nslot; s += stride)
    {
        const float4 m4 = mu4[s];
        const float4 v4 = var4[s];
        const int d0 = ((int)(s & 127)) << 2;
        const float ms[4] = {m4.x, m4.y, m4.z, m4.w};
        const float vs[4] = {v4.x, v4.y, v4.z, v4.w};

        #pragma unroll
        for (int j = 0; j < 4; ++j) {
            const float m = ms[j], v = vs[j];
            if (m < 2.4f * v) continue;                 // u = 0 (s>=16395)
            const int bk = ((d0 + j) << 3) + sh;
            if (m > 6.0f * v) {                         // u = 1, no erfcf
                atomicAdd(&u1c[bk], 1u);
            } else {                                    // band: compact
                const float x = m / v;
                const unsigned int ent = __float_as_uint(x) & 0x00FFFFFFu;
                const unsigned int pos = atomicAdd(&cur[bk], 1u);
                if (pos < (unsigned int)cap) {
                    buf[(size_t)bk * cap + pos] = ent;
                } else {                                // near-impossible spill
                    const unsigned int op = atomicAdd(ovf_cnt, 1u);
                    if (op < (unsigned int)OVFCAP) {
                        ovf[2 * op]     = (unsigned int)(d0 + j);
                        ovf[2 * op + 1] = ent;
                    }
                }
            }
        }
    }
}

// ---------------- pass 2: per-dim LDS histogram + LDS scan ----------------
__global__ __launch_bounds__(256) void fdr_kernel(
    const unsigned int* __restrict__ W, int cap, int* __restrict__ out)
{
    const unsigned int* __restrict__ cur     = W;
    const unsigned int* __restrict__ u1c     = W + 4096;
    const unsigned int* __restrict__ ovf_cnt = W + 8192;
    const unsigned int* __restrict__ ovf     = W + 8200;
    const unsigned int* __restrict__ buf     = W + HDRU32;

    __shared__ unsigned int hist[H32PD];       // packed u16 bins, 30720 B
    __shared__ unsigned int wsum[4], redc[4], redm[4];
    __shared__ unsigned int c1tot;

    const int tid = threadIdx.x, lane = tid & 63, wid = tid >> 6;
    const int d = blockIdx.x;

    #pragma unroll
    for (int i = tid; i < H32PD; i += 256) hist[i] = 0u;
    unsigned int c1 = (tid < NSH) ? u1c[(d << 3) + tid] : 0u;
    __syncthreads();

    // dense erfcf over this dim's compacted entries
    for (int sh = 0; sh < NSH; ++sh) {
        const unsigned int len = min(cur[(d << 3) + sh], (unsigned int)cap);
        const unsigned int* __restrict__ b = buf + (size_t)((d << 3) + sh) * cap;
        for (unsigned int i = tid; i < len; i += 256) {
            const unsigned int ent = b[i];
            const float x = __uint_as_float(0x40000000u | ent);
            const float p = 0.5f * erfcf(x * 0.70710678118654752f);
            const float s = p * 2000000.0f;
            if (s <= (float)UCAP) {
                const int ui = (int)ceilf(s);
                const unsigned int u = (unsigned int)(ui < 1 ? 1 : ui);
                if (u == 1u) c1++;
                else {
                    const unsigned int bi = u - 1u;
                    atomicAdd(&hist[bi >> 1], 1u << ((bi & 1u) << 4));
                }
            }
        }
    }
    // overflow list (expected empty)
    const unsigned int novf = min(*ovf_cnt, (unsigned int)OVFCAP);
    for (unsigned int i = tid; i < novf; i += 256) {
        if (ovf[2 * i] == (unsigned int)d) {
            const float x = __uint_as_float(0x40000000u | ovf[2 * i + 1]);
            const float p = 0.5f * erfcf(x * 0.70710678118654752f);
            const float s = p * 2000000.0f;
            if (s <= (float)UCAP) {
                const int ui = (int)ceilf(s);
                const unsigned int u = (unsigned int)(ui < 1 ? 1 : ui);
                if (u == 1u) c1++;
                else {
                    const unsigned int bi = u - 1u;
                    atomicAdd(&hist[bi >> 1], 1u << ((bi & 1u) << 4));
                }
            }
        }
    }

    // block-reduce c1
    #pragma unroll
    for (int o = 32; o > 0; o >>= 1) c1 += __shfl_down(c1, o, 64);
    if (lane == 0) redc[wid] = c1;
    __syncthreads();
    if (tid == 0) c1tot = redc[0] + redc[1] + redc[2] + redc[3];
    __syncthreads();

    // cumulative scan over 15360 bins (8 chunks of 2048), all in LDS
    unsigned int running = 0, tcount = 0, tmin = 0xFFFFFFFFu;
    for (int u0 = 0; u0 < UCAP; u0 += 2048) {
        const int w0 = (u0 >> 1) + (tid << 2);
        uint4 wv = make_uint4(0u, 0u, 0u, 0u);
        if (w0 < H32PD) wv = *(const uint4*)&hist[w0];
        unsigned int cc[8] = {wv.x & 0xFFFFu, wv.x >> 16, wv.y & 0xFFFFu, wv.y >> 16,
                              wv.z & 0xFFFFu, wv.z >> 16, wv.w & 0xFFFFu, wv.w >> 16};
        if (u0 == 0 && tid == 0) cc[0] += c1tot;       // bin m=1
        unsigned int ls = 0;
        #pragma unroll
        for (int j = 0; j < 8; ++j) ls += cc[j];

        unsigned int sc = ls;                          // wave64 inclusive scan
        #pragma unroll
        for (int dd = 1; dd < 64; dd <<= 1) {
            const unsigned int vv = __shfl_up(sc, dd, 64);
            if (lane >= dd) sc += vv;
        }
        if (lane == 63) wsum[wid] = sc;
        __syncthreads();

        unsigned int woff = 0, btot = 0;
        #pragma unroll
        for (int w = 0; w < 4; ++w) {
            const unsigned int ssum = wsum[w];
            btot += ssum;
            if (w < wid) woff += ssum;
        }

        unsigned int P = running + woff + (sc - ls);   // exclusive prefix
        #pragma unroll
        for (int j = 0; j < 8; ++j) {
            P += cc[j];                                // inclusive C(m)
            const unsigned int mm = (unsigned int)(u0 + (tid << 3) + j + 1);
            if (mm <= (unsigned int)UCAP && P >= mm) {
                tcount++; if (mm < tmin) tmin = mm;
            }
        }
        running += btot;
        __syncthreads();
    }

    #pragma unroll
    for (int dd = 32; dd > 0; dd >>= 1) {
        tcount += __shfl_down(tcount, dd, 64);
        const unsigned int om = __shfl_down(tmin, dd, 64);
        if (om < tmin) tmin = om;
    }
    if (lane == 0) { redc[wid] = tcount; redm[wid] = tmin; }
    __syncthreads();
    if (tid == 0) {
        const unsigned int tot = redc[0] + redc[1] + redc[2] + redc[3];
        const unsigned int mn  = min(min(redm[0], redm[1]), min(redm[2], redm[3]));
        out[d] = tot ? (int)(tot + mn - 1u) : 0;
    }
}

extern "C" void kernel_launch(void* const* d_in, const int* in_sizes, int n_in,
                              void* d_out, int out_size, void* d_ws, size_t ws_size,
                              hipStream_t stream)
{
    const float4* mu4  = (const float4*)d_in[0];
    const float4* var4 = (const float4*)d_in[1];
    int* out = (int*)d_out;
    unsigned int* W = (unsigned int*)d_ws;

    // bucket capacity from ws (expected mean 1363/bucket; ws>=51.2MB -> ~3250)
    const size_t ws_u32 = ws_size / 4;
    long avail = (long)ws_u32 - (long)HDRU32;
    long capl = avail > 0 ? avail / NBUCK : 1;
    if (capl < 1) capl = 1;
    if (capl > 8192) capl = 8192;
    const int cap = (int)capl;

    zero_kernel<<<33, 256, 0, stream>>>(W);
    classify_kernel<<<8192, 256, 0, stream>>>(mu4, var4, W, cap);
    fdr_kernel<<<N_DIM, 256, 0, stream>>>(W, cap, out);
}

// Round 6
// 667.667 us; speedup vs baseline: 1.2580x; 1.0578x over previous
//
#include <hip/hip_runtime.h>
#include <cstdint>
#include <cstddef>

// DimensionPruning: per-dim BH-FDR rejection count.
// importance[d] = #{m: C_d(m) >= m} + min{m: C_d(m) >= m} - 1  (0 if none)
// C_d(m) = #{i: u_i <= m}, u_i = ceil(p_i * n/alpha), p_i = Phi(-mu/sigma).
//
// Round-6 = round-4 resubmit (rounds 4 and 5 died in the container broker
// before any kernel ran; failure signature is push/acquire-side).
// Design rationale:
//  * round-3's 403us classify at 8% VALU / 14% BW / 88% occupancy = memory-
//    side atomic-line serialization; cur/u1c were DENSE 16KB arrays -> ~16
//    counters (all 8 XCD shards!) per 128B line, 8M atomics over ~256 hot
//    lines = unhideable serialization.
//  * fix: every cursor / u1 counter gets a PRIVATE 128B line (PAD=32 u32).
//  * classify: lean grid-stride stream (gates proven exact three times).
//  * ucompute: full-occupancy pass rewriting each compacted band entry in
//    place as its u value (dense erfcf, full-lane waves).
//  * fdr: per-dim block reads u values (uint4-vectorized), LDS u16 hist +
//    LDS scan. erfcf only for the (expected-empty) overflow list.
// Exactness: identical fp sequences to the verified round-3 kernel; gates:
// s(2.4)=16395>15360 -> u=0; s(6)=0.002 -> ceil-clamp u=1. x in [2.4,6]
// spans exponents {128,129} -> 24-bit entry, rebuilt as 0x40000000|ent.
// ws evidence: round-0 chose D_c=256 (FETCH=200MB/dispatch) -> ws in
// [51.2,102.4) MB -> cap >= 3044 (+45 sigma over 1363 mean fill).

#define N_OBJ  100000
#define N_DIM  512
#define UCAP   15360
#define H32PD  (UCAP / 2)            // 7680 packed-u16 words per dim (LDS)
#define NSH    8                     // shards (blockIdx&7 ~ XCD)
#define NBUCK  (N_DIM * NSH)         // 4096 buckets
#define PAD    32                    // u32 per counter -> 128B private line
#define OVFCAP 32768

// ws u32 layout
#define CURBASE 0
#define U1BASE  (NBUCK * PAD)                 // 131072
#define OVFCNT  (2 * NBUCK * PAD)             // 262144
#define OVFBASE (OVFCNT + 8)
#define HDRU32  (OVFBASE + 2 * OVFCAP)        // 327688 (16B-aligned in bytes)

// ---------------- pass 0: zero padded counters + ovf count ----------------
__global__ __launch_bounds__(256) void zero_kernel(unsigned int* __restrict__ w)
{
    const int i = blockIdx.x * 256 + threadIdx.x;
    if (i < OVFCNT + 1) w[i] = 0u;
}

// ---------------- pass 1: lean classify + compact ----------------
__global__ __launch_bounds__(256) void classify_kernel(
    const float4* __restrict__ mu4, const float4* __restrict__ var4,
    unsigned int* __restrict__ W, int cap)
{
    unsigned int* __restrict__ cur     = W + CURBASE;
    unsigned int* __restrict__ u1c     = W + U1BASE;
    unsigned int* __restrict__ ovf_cnt = W + OVFCNT;
    unsigned int* __restrict__ ovf     = W + OVFBASE;
    unsigned int* __restrict__ buf     = W + HDRU32;

    const int sh = blockIdx.x & (NSH - 1);
    const size_t nslot  = (size_t)N_OBJ * N_DIM / 4;   // 12,800,000
    const size_t stride = (size_t)gridDim.x * 256;

    for (size_t s = (size_t)blockIdx.x * 256 + threadIdx.x; s < nslot; s += stride)
    {
        const float4 m4 = mu4[s];
        const float4 v4 = var4[s];
        const int d0 = ((int)(s & 127)) << 2;
        const float ms[4] = {m4.x, m4.y, m4.z, m4.w};
        const float vs[4] = {v4.x, v4.y, v4.z, v4.w};

        #pragma unroll
        for (int j = 0; j < 4; ++j) {
            const float m = ms[j], v = vs[j];
            if (m < 2.4f * v) continue;                 // u = 0 (s>=16395)
            const int bk = ((d0 + j) << 3) + sh;
            if (m > 6.0f * v) {                         // u = 1, no erfcf
                atomicAdd(&u1c[bk << 5], 1u);           // private 128B line
            } else {                                    // band: compact
                const float x = m / v;
                const unsigned int ent = __float_as_uint(x) & 0x00FFFFFFu;
                const unsigned int pos = atomicAdd(&cur[bk << 5], 1u);
                if (pos < (unsigned int)cap) {
                    buf[(size_t)bk * cap + pos] = ent;
                } else {                                // near-impossible spill
                    const unsigned int op = atomicAdd(ovf_cnt, 1u);
                    if (op < (unsigned int)OVFCAP) {
                        ovf[2 * op]     = (unsigned int)(d0 + j);
                        ovf[2 * op + 1] = ent;
                    }
                }
            }
        }
    }
}

// ---------------- pass 2: dense erfcf, entry -> u, in place ----------------
__global__ __launch_bounds__(256) void ucompute_kernel(
    unsigned int* __restrict__ W, int cap, int nbpb)
{
    const unsigned int* __restrict__ cur = W + CURBASE;
    unsigned int* __restrict__ buf       = W + HDRU32;

    const int bk  = blockIdx.x / nbpb;
    const int sub = blockIdx.x - bk * nbpb;
    const unsigned int len = min(cur[bk << 5], (unsigned int)cap);
    const unsigned int i = (unsigned int)(sub * 256 + threadIdx.x);
    if (i >= len) return;

    unsigned int* __restrict__ b = buf + (size_t)bk * cap;
    const unsigned int ent = b[i];
    const float x = __uint_as_float(0x40000000u | ent);
    const float p = 0.5f * erfcf(x * 0.70710678118654752f);
    const float s = p * 2000000.0f;
    unsigned int u = 0u;
    if (s <= (float)UCAP) {
        const int ui = (int)ceilf(s);
        u = (unsigned int)(ui < 1 ? 1 : ui);
    }
    b[i] = u;                                           // overwrite entry with u
}

// ---------------- pass 3: per-dim LDS histogram + LDS scan ----------------
__device__ __forceinline__ void bin_u(unsigned int u, unsigned int& c1,
                                      unsigned int* hist)
{
    if (u == 0u) return;
    if (u == 1u) { c1++; return; }
    const unsigned int bi = u - 1u;
    atomicAdd(&hist[bi >> 1], 1u << ((bi & 1u) << 4));
}

__global__ __launch_bounds__(256) void fdr_kernel(
    const unsigned int* __restrict__ W, int cap, int* __restrict__ out)
{
    const unsigned int* __restrict__ cur     = W + CURBASE;
    const unsigned int* __restrict__ u1c     = W + U1BASE;
    const unsigned int* __restrict__ ovf_cnt = W + OVFCNT;
    const unsigned int* __restrict__ ovf     = W + OVFBASE;
    const unsigned int* __restrict__ buf     = W + HDRU32;

    __shared__ unsigned int hist[H32PD];       // packed u16 bins, 30720 B
    __shared__ unsigned int wsum[4], redc[4], redm[4];
    __shared__ unsigned int c1tot;

    const int tid = threadIdx.x, lane = tid & 63, wid = tid >> 6;
    const int d = blockIdx.x;

    for (int i = tid; i < H32PD; i += 256) hist[i] = 0u;
    unsigned int c1 = (tid < NSH) ? u1c[((d << 3) + tid) << 5] : 0u;
    __syncthreads();

    // u values for this dim (uint4-vectorized; cap is a multiple of 4)
    for (int sh = 0; sh < NSH; ++sh) {
        const unsigned int len = min(cur[((d << 3) + sh) << 5], (unsigned int)cap);
        const unsigned int* __restrict__ b = buf + (size_t)((d << 3) + sh) * cap;
        const uint4* __restrict__ b4 = (const uint4*)b;
        for (unsigned int i = tid; i < (len >> 2); i += 256) {
            const uint4 w = b4[i];
            bin_u(w.x, c1, hist); bin_u(w.y, c1, hist);
            bin_u(w.z, c1, hist); bin_u(w.w, c1, hist);
        }
        for (unsigned int i = (len & ~3u) + tid; i < len; i += 256)
            bin_u(b[i], c1, hist);
    }
    // overflow list (expected empty): erfcf inline
    const unsigned int novf = min(*ovf_cnt, (unsigned int)OVFCAP);
    for (unsigned int i = tid; i < novf; i += 256) {
        if (ovf[2 * i] == (unsigned int)d) {
            const float x = __uint_as_float(0x40000000u | ovf[2 * i + 1]);
            const float p = 0.5f * erfcf(x * 0.70710678118654752f);
            const float s = p * 2000000.0f;
            if (s <= (float)UCAP) {
                const int ui = (int)ceilf(s);
                bin_u((unsigned int)(ui < 1 ? 1 : ui), c1, hist);
            }
        }
    }

    // block-reduce c1
    #pragma unroll
    for (int o = 32; o > 0; o >>= 1) c1 += __shfl_down(c1, o, 64);
    if (lane == 0) redc[wid] = c1;
    __syncthreads();
    if (tid == 0) c1tot = redc[0] + redc[1] + redc[2] + redc[3];
    __syncthreads();

    // cumulative scan over 15360 bins (8 chunks of 2048), all in LDS
    unsigned int running = 0, tcount = 0, tmin = 0xFFFFFFFFu;
    for (int u0 = 0; u0 < UCAP; u0 += 2048) {
        const int w0 = (u0 >> 1) + (tid << 2);
        uint4 wv = make_uint4(0u, 0u, 0u, 0u);
        if (w0 < H32PD) wv = *(const uint4*)&hist[w0];
        unsigned int cc[8] = {wv.x & 0xFFFFu, wv.x >> 16, wv.y & 0xFFFFu, wv.y >> 16,
                              wv.z & 0xFFFFu, wv.z >> 16, wv.w & 0xFFFFu, wv.w >> 16};
        if (u0 == 0 && tid == 0) cc[0] += c1tot;       // bin m=1
        unsigned int ls = 0;
        #pragma unroll
        for (int j = 0; j < 8; ++j) ls += cc[j];

        unsigned int sc = ls;                          // wave64 inclusive scan
        #pragma unroll
        for (int dd = 1; dd < 64; dd <<= 1) {
            const unsigned int vv = __shfl_up(sc, dd, 64);
            if (lane >= dd) sc += vv;
        }
        if (lane == 63) wsum[wid] = sc;
        __syncthreads();

        unsigned int woff = 0, btot = 0;
        #pragma unroll
        for (int w = 0; w < 4; ++w) {
            const unsigned int ssum = wsum[w];
            btot += ssum;
            if (w < wid) woff += ssum;
        }

        unsigned int P = running + woff + (sc - ls);   // exclusive prefix
        #pragma unroll
        for (int j = 0; j < 8; ++j) {
            P += cc[j];                                // inclusive C(m)
            const unsigned int mm = (unsigned int)(u0 + (tid << 3) + j + 1);
            if (mm <= (unsigned int)UCAP && P >= mm) {
                tcount++; if (mm < tmin) tmin = mm;
            }
        }
        running += btot;
        __syncthreads();
    }

    #pragma unroll
    for (int dd = 32; dd > 0; dd >>= 1) {
        tcount += __shfl_down(tcount, dd, 64);
        const unsigned int om = __shfl_down(tmin, dd, 64);
        if (om < tmin) tmin = om;
    }
    if (lane == 0) { redc[wid] = tcount; redm[wid] = tmin; }
    __syncthreads();
    if (tid == 0) {
        const unsigned int tot = redc[0] + redc[1] + redc[2] + redc[3];
        const unsigned int mn  = min(min(redm[0], redm[1]), min(redm[2], redm[3]));
        out[d] = tot ? (int)(tot + mn - 1u) : 0;
    }
}

extern "C" void kernel_launch(void* const* d_in, const int* in_sizes, int n_in,
                              void* d_out, int out_size, void* d_ws, size_t ws_size,
                              hipStream_t stream)
{
    const float4* mu4  = (const float4*)d_in[0];
    const float4* var4 = (const float4*)d_in[1];
    int* out = (int*)d_out;
    unsigned int* W = (unsigned int*)d_ws;

    // bucket capacity (u32 entries) from ws; multiple of 4 for uint4 reads.
    // expected fill ~1363/bucket; ws=51.2MB -> cap ~3044 (+45 sigma).
    const size_t ws_u32 = ws_size / 4;
    long avail = (long)ws_u32 - (long)HDRU32;
    long capl = avail > 0 ? avail / NBUCK : 4;
    capl &= ~3L;
    if (capl < 4) capl = 4;
    if (capl > 8192) capl = 8192;
    const int cap = (int)capl;
    const int nbpb = (cap + 255) / 256;            // sub-blocks per bucket

    zero_kernel<<<(OVFCNT + 256) / 256 + 1, 256, 0, stream>>>(W);
    classify_kernel<<<8192, 256, 0, stream>>>(mu4, var4, W, cap);
    ucompute_kernel<<<NBUCK * nbpb, 256, 0, stream>>>(W, cap, nbpb);
    fdr_kernel<<<N_DIM, 256, 0, stream>>>(W, cap, out);
}